// Round 1
// baseline (605.606 us; speedup 1.0000x reference)
//
#include <hip/hip_runtime.h>
#include <math.h>

#define FFT_THREADS 256

constexpr int NFFT = 524288;   // 2^19 >= T + L - 1 = 485099
constexpr int N1   = 1024;     // stage-1 (column) FFT length
constexpr int LOG1 = 10;
constexpr int N2   = 512;      // stage-2 (row) FFT length
constexpr int LOG2 = 9;
constexpr int TT   = 441000;
constexpr int IRL  = 44100;
constexpr int NSIG = 16;       // 32 real batches packed as 16 complex signals
constexpr int C1   = 2;        // columns per workgroup in stage1/3
constexpr int R2   = 4;        // rows per workgroup in stage2

__device__ inline float2 cmulf(float2 a, float2 b) {
    return make_float2(a.x * b.x - a.y * b.y, a.x * b.y + a.y * b.x);
}

// Radix-2 Stockham FFT over C interleaved sequences held in LDS.
// Sequence c occupies [c*(L+1), c*(L+1)+L) in both ping-pong buffers
// (+1 pad breaks the power-of-2 bank stride between sequences).
// twl[j] = W_L^j (forward sign), j < L/2. inverse => conjugate on use.
// Returns the buffer holding the (natural-order) result.
template<int L, int LOGL, int C>
__device__ float2* lds_fft_multi(float2* b0, float2* b1, const float2* twl, bool inverse) {
    float2* cur = b0;
    float2* nxt = b1;
    int s = 1, logs = 0, nn = L;
    constexpr int BUT = C * (L / 2);
    for (int pass = 0; pass < LOGL; ++pass) {
        for (int f0 = threadIdx.x; f0 < BUT; f0 += FFT_THREADS) {
            const int f = f0 & (L / 2 - 1);
            const int c = f0 >> (LOGL - 1);
            const int q = f & (s - 1);
            const int p = f >> logs;
            const int base = c * (L + 1);
            // reads: q + s*p == f  and  f + s*m == f + L/2  -> coalesced, conflict-free
            float2 a = cur[base + f];
            float2 b = cur[base + f + (L / 2)];
            float2 w = twl[p * s];
            if (inverse) w.y = -w.y;
            float2 dif = make_float2(a.x - b.x, a.y - b.y);
            const int w1 = base + f + s * p;       // q + 2*s*p
            nxt[w1]     = make_float2(a.x + b.x, a.y + b.y);
            nxt[w1 + s] = cmulf(dif, w);
        }
        __syncthreads();
        float2* t = cur; cur = nxt; nxt = t;
        nn >>= 1; s <<= 1; ++logs;
    }
    (void)nn;
    return cur;
}

// gtable[j] = exp(-2*pi*i*j/NFFT)
__global__ __launch_bounds__(256) void k_table(float2* __restrict__ gtable) {
    int j = blockIdx.x * 256 + threadIdx.x;
    if (j < NFFT) {
        float ang = -6.2831853071795864769f * ((float)j * (1.0f / (float)NFFT));
        gtable[j] = make_float2(cosf(ang), sinf(ang));
    }
}

// Stage 1 (forward): column FFTs of length N1 over n1 (stride N2) + twiddle W_N^{n2*k1}.
// sig < NSIG: complex pack of batches (2*sig, 2*sig+1), zero-padded past TT.
// sig == NSIG: the IR (imag = 0), zero-padded past IRL. Output layout [k1][n2].
__global__ __launch_bounds__(256) void k_stage1(const float* __restrict__ x,
                                                const float* __restrict__ ir,
                                                const float2* __restrict__ gtable,
                                                float2* __restrict__ bufA,
                                                float2* __restrict__ irA) {
    __shared__ float2 b0[C1 * (N1 + 1)];
    __shared__ float2 b1[C1 * (N1 + 1)];
    __shared__ float2 twl[N1 / 2];
    const int sig  = blockIdx.y;
    const int col0 = blockIdx.x * C1;

    for (int j = threadIdx.x; j < N1 / 2; j += 256) twl[j] = gtable[j * (NFFT / N1)];

    for (int p = threadIdx.x; p < C1 * N1; p += 256) {
        const int c = p & (C1 - 1), n1 = p >> 1;
        const int n = n1 * N2 + col0 + c;
        float2 v;
        if (sig < NSIG) {
            v.x = (n < TT) ? x[(size_t)(2 * sig) * TT + n] : 0.0f;
            v.y = (n < TT) ? x[(size_t)(2 * sig + 1) * TT + n] : 0.0f;
        } else {
            v.x = (n < IRL) ? ir[n] : 0.0f;
            v.y = 0.0f;
        }
        b0[c * (N1 + 1) + n1] = v;
    }
    __syncthreads();

    float2* res = lds_fft_multi<N1, LOG1, C1>(b0, b1, twl, false);

    float2* dst = (sig < NSIG) ? (bufA + (size_t)sig * NFFT) : irA;
    for (int p = threadIdx.x; p < C1 * N1; p += 256) {
        const int c = p & (C1 - 1), k1 = p >> 1;
        const int n2 = col0 + c;
        float2 v = res[c * (N1 + 1) + k1];
        float2 w = gtable[(n2 * k1) & (NFFT - 1)];
        dst[(size_t)k1 * N2 + n2] = cmulf(v, w);
    }
}

// Stage 2: row FFTs of length N2 (contiguous).
// mode 0 (IR): forward FFT only -> Ht[k1][k2] (true DFT, transposed layout).
// mode 1 (x) : forward FFT, multiply by Ht, inverse FFT, conj twiddle W_N^{-n2*k1}.
__global__ __launch_bounds__(256) void k_stage2(const float2* __restrict__ src,
                                                float2* __restrict__ dst,
                                                const float2* __restrict__ Ht,
                                                const float2* __restrict__ gtable,
                                                int mode) {
    __shared__ float2 b0[R2 * (N2 + 1)];
    __shared__ float2 b1[R2 * (N2 + 1)];
    __shared__ float2 twl[N2 / 2];
    const int r0 = blockIdx.x * R2;   // flat row = sig*N1 + k1 (mode1) or k1 (mode0)

    for (int j = threadIdx.x; j < N2 / 2; j += 256) twl[j] = gtable[j * (NFFT / N2)];

    for (int p = threadIdx.x; p < R2 * N2; p += 256) {
        const int rr = p >> LOG2, k2 = p & (N2 - 1);
        b0[rr * (N2 + 1) + k2] = src[(size_t)(r0 + rr) * N2 + k2];
    }
    __syncthreads();

    float2* res = lds_fft_multi<N2, LOG2, R2>(b0, b1, twl, false);

    if (mode == 0) {
        for (int p = threadIdx.x; p < R2 * N2; p += 256) {
            const int rr = p >> LOG2, k2 = p & (N2 - 1);
            dst[(size_t)(r0 + rr) * N2 + k2] = res[rr * (N2 + 1) + k2];
        }
        return;
    }

    // pointwise spectral multiply (transposed layouts match by construction)
    for (int p = threadIdx.x; p < R2 * N2; p += 256) {
        const int rr = p >> LOG2, k2 = p & (N2 - 1);
        const int k1 = (r0 + rr) & (N1 - 1);
        const int li = rr * (N2 + 1) + k2;
        res[li] = cmulf(res[li], Ht[(size_t)k1 * N2 + k2]);
    }
    __syncthreads();

    float2* other = (res == b0) ? b1 : b0;
    float2* res2 = lds_fft_multi<N2, LOG2, R2>(res, other, twl, true);

    for (int p = threadIdx.x; p < R2 * N2; p += 256) {
        const int rr = p >> LOG2, n2 = p & (N2 - 1);
        const int k1 = (r0 + rr) & (N1 - 1);
        float2 v = res2[rr * (N2 + 1) + n2];
        float2 w = gtable[(n2 * k1) & (NFFT - 1)];
        w.y = -w.y;   // inverse twiddle
        dst[(size_t)(r0 + rr) * N2 + n2] = cmulf(v, w);
    }
}

// Stage 3 (inverse): column IFFTs of length N1 over k1, scale 1/N, unpack
// complex -> two real batches, fuse wet/dry mix, write n < TT only.
__global__ __launch_bounds__(256) void k_stage3(const float2* __restrict__ bufB,
                                                const float* __restrict__ x,
                                                const float* __restrict__ wet_param,
                                                const float2* __restrict__ gtable,
                                                float* __restrict__ out) {
    __shared__ float2 b0[C1 * (N1 + 1)];
    __shared__ float2 b1[C1 * (N1 + 1)];
    __shared__ float2 twl[N1 / 2];
    const int sig  = blockIdx.y;
    const int col0 = blockIdx.x * C1;

    for (int j = threadIdx.x; j < N1 / 2; j += 256) twl[j] = gtable[j * (NFFT / N1)];

    const float2* src = bufB + (size_t)sig * NFFT;
    for (int p = threadIdx.x; p < C1 * N1; p += 256) {
        const int c = p & (C1 - 1), k1 = p >> 1;
        b0[c * (N1 + 1) + k1] = src[(size_t)k1 * N2 + col0 + c];
    }
    __syncthreads();

    float2* res = lds_fft_multi<N1, LOG1, C1>(b0, b1, twl, true);

    const float wp  = wet_param[0];
    const float wet = 1.0f / (1.0f + expf(-wp));
    const float dry = 1.0f - wet;
    const float scale = 1.0f / (float)NFFT;

    for (int p = threadIdx.x; p < C1 * N1; p += 256) {
        const int c = p & (C1 - 1), n1 = p >> 1;
        const int n = n1 * N2 + col0 + c;
        if (n < TT) {
            float2 v = res[c * (N1 + 1) + n1];
            const size_t ia = (size_t)(2 * sig) * TT + n;
            const size_t ib = (size_t)(2 * sig + 1) * TT + n;
            out[ia] = dry * x[ia] + wet * (v.x * scale);
            out[ib] = dry * x[ib] + wet * (v.y * scale);
        }
    }
}

// Correctness fallback if workspace is too small: direct time-domain conv.
__global__ __launch_bounds__(256) void k_direct(const float* __restrict__ x,
                                                const float* __restrict__ ir,
                                                const float* __restrict__ wet_param,
                                                float* __restrict__ out) {
    __shared__ float irs[1024];
    const int b = blockIdx.y;
    const int n = blockIdx.x * 256 + threadIdx.x;
    float acc = 0.0f;
    for (int k0 = 0; k0 < IRL; k0 += 1024) {
        __syncthreads();
        for (int j = threadIdx.x; j < 1024; j += 256) {
            const int k = k0 + j;
            irs[j] = (k < IRL) ? ir[k] : 0.0f;
        }
        __syncthreads();
        if (n < TT) {
            const int kend = min(1024, n - k0 + 1);
            for (int k = 0; k < kend; ++k)
                acc += irs[k] * x[(size_t)b * TT + (n - k0 - k)];
        }
    }
    if (n < TT) {
        const float wet = 1.0f / (1.0f + expf(-wet_param[0]));
        out[(size_t)b * TT + n] = (1.0f - wet) * x[(size_t)b * TT + n] + wet * acc;
    }
}

extern "C" void kernel_launch(void* const* d_in, const int* in_sizes, int n_in,
                              void* d_out, int out_size, void* d_ws, size_t ws_size,
                              hipStream_t stream) {
    (void)in_sizes; (void)n_in; (void)out_size;
    const float* x   = (const float*)d_in[0];
    const float* ir  = (const float*)d_in[1];
    const float* wet = (const float*)d_in[2];
    float* out = (float*)d_out;

    // workspace: gtable (N) + Ht (N) + bufA (16*N) + bufB (16*N), float2 each
    const size_t need = (size_t)(2 + 2 * NSIG) * NFFT * sizeof(float2);
    if (ws_size < need) {
        dim3 g((TT + 255) / 256, 32);
        k_direct<<<g, 256, 0, stream>>>(x, ir, wet, out);
        return;
    }

    float2* gtable = (float2*)d_ws;
    float2* Ht     = gtable + NFFT;
    float2* bufA   = Ht + NFFT;
    float2* bufB   = bufA + (size_t)NSIG * NFFT;
    float2* irA    = bufB;   // reuse bufB[0] region before it is written

    k_table<<<dim3(NFFT / 256), 256, 0, stream>>>(gtable);
    // 17th signal (blockIdx.y == NSIG) is the IR
    k_stage1<<<dim3(N2 / C1, NSIG + 1), 256, 0, stream>>>(x, ir, gtable, bufA, irA);
    k_stage2<<<dim3(N1 / R2), 256, 0, stream>>>(irA, Ht, gtable, gtable, 0);
    k_stage2<<<dim3(NSIG * N1 / R2), 256, 0, stream>>>(bufA, bufB, Ht, gtable, 1);
    k_stage3<<<dim3(N2 / C1, NSIG), 256, 0, stream>>>(bufB, x, wet, gtable, out);
}

// Round 2
// 354.070 us; speedup vs baseline: 1.7104x; 1.7104x over previous
//
#include <hip/hip_runtime.h>
#include <math.h>

constexpr int NFFT = 524288;   // 2^19 >= T + L - 1 = 485099
constexpr int N1   = 512;      // column FFT length (strided dim)
constexpr int LOG1 = 9;
constexpr int N2   = 1024;     // row FFT length (contiguous dim)
constexpr int LOG2 = 10;
constexpr int TT   = 441000;
constexpr int IRL  = 44100;
constexpr int NSIG = 16;       // 32 real batches packed as 16 complex signals
constexpr int C1   = 16;       // columns per block in stage1/3 (128B segments)
constexpr int R2   = 4;        // rows per block in stage2

// -2*pi/NFFT
constexpr float ANG0 = -1.1984224905891939e-5f;

__device__ inline float2 cmulf(float2 a, float2 b) {
    return make_float2(a.x * b.x - a.y * b.y, a.x * b.y + a.y * b.x);
}

// Compact twiddle tables: tw1024[j]=W_1024^j (512 entries) then tw512[j]=W_512^j (256).
__global__ __launch_bounds__(256) void k_table(float2* __restrict__ t) {
    int j = blockIdx.x * 256 + threadIdx.x;
    if (j < 512) {
        float a = -6.2831853071795864769f * (float)j * (1.0f / 1024.0f);
        t[j] = make_float2(cosf(a), sinf(a));
    }
    if (j < 256) {
        float a = -6.2831853071795864769f * (float)j * (1.0f / 512.0f);
        t[512 + j] = make_float2(cosf(a), sinf(a));
    }
}

// In-place Stockham FFT: 16 sequences of length 512 in one 64KB LDS buffer.
// Element idx of sequence c lives at c*512 + (idx ^ c)  (XOR swizzle kills the
// 16-way bank conflict of the stride-512 transpose phases; FFT phases see a
// wave-uniform c, so their bank patterns are unchanged).
// Thread tid owns butterfly f = tid of every sequence (256 threads, L/2 = 256).
template<bool INV>
__device__ void fft512x16(float2* buf, const float2* __restrict__ tw) {
    const int f = threadIdx.x;
    int s = 1, logs = 0;
    for (int pass = 0; pass < LOG1; ++pass) {
        const int p  = f >> logs;
        const int w1 = f + s * p;              // q + 2*s*p
        float2 w = tw[(f >> logs) << logs];    // tw[p*s], one load per pass
        if (INV) w.y = -w.y;
        float2 a[16], b[16];
#pragma unroll
        for (int c = 0; c < 16; ++c) {
            a[c] = buf[c * N1 + (f ^ c)];
            b[c] = buf[c * N1 + ((f + 256) ^ c)];
        }
        __syncthreads();
#pragma unroll
        for (int c = 0; c < 16; ++c) {
            float2 sum = make_float2(a[c].x + b[c].x, a[c].y + b[c].y);
            float2 dif = make_float2(a[c].x - b[c].x, a[c].y - b[c].y);
            buf[c * N1 + (w1 ^ c)]       = sum;
            buf[c * N1 + ((w1 + s) ^ c)] = cmulf(dif, w);
        }
        __syncthreads();
        s <<= 1; ++logs;
    }
}

// Ping-pong Stockham over C sequences of length L (contiguous, no pad).
template<int L, int LOGL, int C>
__device__ float2* lds_fft_pp(float2* b0, float2* b1, const float2* __restrict__ tw,
                              bool inverse) {
    float2* cur = b0;
    float2* nxt = b1;
    int s = 1, logs = 0;
    constexpr int BUT = C * (L / 2);
    for (int pass = 0; pass < LOGL; ++pass) {
        for (int f0 = threadIdx.x; f0 < BUT; f0 += 256) {
            const int f = f0 & (L / 2 - 1);
            const int c = f0 >> (LOGL - 1);
            const int p = f >> logs;
            const int base = c * L;
            float2 a = cur[base + f];
            float2 b = cur[base + f + (L / 2)];
            float2 w = tw[(f >> logs) << logs];   // tw[p*s]
            if (inverse) w.y = -w.y;
            float2 dif = make_float2(a.x - b.x, a.y - b.y);
            const int w1 = base + f + s * p;
            nxt[w1]     = make_float2(a.x + b.x, a.y + b.y);
            nxt[w1 + s] = cmulf(dif, w);
        }
        __syncthreads();
        float2* t = cur; cur = nxt; nxt = t;
        s <<= 1; ++logs;
    }
    return cur;
}

// Stage 1 (forward): column FFTs of length N1=512 over n1 (stride N2) for 16
// consecutive n2 per block + inter-stage twiddle W_N^{n2*k1}. Output [k1][n2].
__global__ __launch_bounds__(256) void k_stage1(const float* __restrict__ x,
                                                const float* __restrict__ ir,
                                                const float2* __restrict__ tw512,
                                                float2* __restrict__ bufA,
                                                float2* __restrict__ irA) {
    __shared__ float2 buf[C1 * N1];   // exactly 64 KB
    const int sig  = blockIdx.y;
    const int col0 = blockIdx.x * C1;

#pragma unroll
    for (int it = 0; it < C1 * N1 / 256; ++it) {
        const int p  = threadIdx.x + 256 * it;
        const int c  = p & (C1 - 1);
        const int n1 = p >> 4;
        const int n  = n1 * N2 + col0 + c;      // 64B-contiguous per (n1, batch)
        float2 v = make_float2(0.0f, 0.0f);
        if (sig < NSIG) {
            if (n < TT) {
                v.x = x[(size_t)(2 * sig) * TT + n];
                v.y = x[(size_t)(2 * sig + 1) * TT + n];
            }
        } else {
            if (n < IRL) v.x = ir[n];
        }
        buf[c * N1 + (n1 ^ c)] = v;
    }
    __syncthreads();

    fft512x16<false>(buf, tw512);

    float2* dst = (sig < NSIG) ? (bufA + (size_t)sig * NFFT) : irA;
#pragma unroll
    for (int it = 0; it < C1 * N1 / 256; ++it) {
        const int p  = threadIdx.x + 256 * it;
        const int c  = p & (C1 - 1);
        const int k1 = p >> 4;
        const int n2 = col0 + c;
        float2 v = buf[c * N1 + (k1 ^ c)];
        float ang = ANG0 * (float)(n2 * k1);    // exact: n2*k1 < 2^24
        float sn, cs;
        __sincosf(ang, &sn, &cs);
        dst[(size_t)k1 * N2 + n2] = cmulf(v, make_float2(cs, sn));  // 128B segments
    }
}

// Stage 2: row FFTs of length N2=1024 (contiguous).
// mode 0 (IR): forward FFT only -> Ht[k1][k2] (transposed spectrum).
// mode 1 (x) : forward FFT, * Ht, inverse FFT, conj twiddle W_N^{-n2*k1}.
__global__ __launch_bounds__(256) void k_stage2(const float2* __restrict__ src,
                                                float2* __restrict__ dst,
                                                const float2* __restrict__ Ht,
                                                const float2* __restrict__ tw1024,
                                                int mode) {
    __shared__ float2 b0[R2 * N2];    // 32 KB
    __shared__ float2 b1[R2 * N2];    // 32 KB
    const int r0 = blockIdx.x * R2;   // flat row = sig*N1 + k1 (mode1) or k1 (mode0)

    for (int p = threadIdx.x; p < R2 * N2; p += 256) {
        const int rr = p >> LOG2, k2 = p & (N2 - 1);
        b0[rr * N2 + k2] = src[(size_t)(r0 + rr) * N2 + k2];
    }
    __syncthreads();

    float2* res = lds_fft_pp<N2, LOG2, R2>(b0, b1, tw1024, false);

    if (mode == 0) {
        for (int p = threadIdx.x; p < R2 * N2; p += 256) {
            const int rr = p >> LOG2, k2 = p & (N2 - 1);
            dst[(size_t)(r0 + rr) * N2 + k2] = res[rr * N2 + k2];
        }
        return;
    }

    for (int p = threadIdx.x; p < R2 * N2; p += 256) {
        const int rr = p >> LOG2, k2 = p & (N2 - 1);
        const int k1 = (r0 + rr) & (N1 - 1);
        const int li = rr * N2 + k2;
        res[li] = cmulf(res[li], Ht[(size_t)k1 * N2 + k2]);
    }
    __syncthreads();

    float2* other = (res == b0) ? b1 : b0;
    float2* res2 = lds_fft_pp<N2, LOG2, R2>(res, other, tw1024, true);

    for (int p = threadIdx.x; p < R2 * N2; p += 256) {
        const int rr = p >> LOG2, n2 = p & (N2 - 1);
        const int k1 = (r0 + rr) & (N1 - 1);
        float2 v = res2[rr * N2 + n2];
        float ang = -ANG0 * (float)(n2 * k1);   // conjugate twiddle
        float sn, cs;
        __sincosf(ang, &sn, &cs);
        dst[(size_t)(r0 + rr) * N2 + n2] = cmulf(v, make_float2(cs, sn));
    }
}

// Stage 3 (inverse): column IFFTs over k1 for 16 consecutive n2 per block,
// scale 1/N, unpack complex -> two real batches, fuse wet/dry mix.
__global__ __launch_bounds__(256) void k_stage3(const float2* __restrict__ bufB,
                                                const float* __restrict__ x,
                                                const float* __restrict__ wet_param,
                                                const float2* __restrict__ tw512,
                                                float* __restrict__ out) {
    __shared__ float2 buf[C1 * N1];   // exactly 64 KB
    const int sig  = blockIdx.y;
    const int col0 = blockIdx.x * C1;

    const float2* src = bufB + (size_t)sig * NFFT;
#pragma unroll
    for (int it = 0; it < C1 * N1 / 256; ++it) {
        const int p  = threadIdx.x + 256 * it;
        const int c  = p & (C1 - 1);
        const int k1 = p >> 4;
        buf[c * N1 + (k1 ^ c)] = src[(size_t)k1 * N2 + col0 + c];   // 128B segments
    }
    __syncthreads();

    fft512x16<true>(buf, tw512);

    const float wet = 1.0f / (1.0f + expf(-wet_param[0]));
    const float dry = 1.0f - wet;
    const float scale = 1.0f / (float)NFFT;

#pragma unroll
    for (int it = 0; it < C1 * N1 / 256; ++it) {
        const int p  = threadIdx.x + 256 * it;
        const int c  = p & (C1 - 1);
        const int n1 = p >> 4;
        const int n  = n1 * N2 + col0 + c;
        if (n < TT) {
            float2 v = buf[c * N1 + (n1 ^ c)];
            const size_t ia = (size_t)(2 * sig) * TT + n;
            const size_t ib = ia + TT;
            out[ia] = dry * x[ia] + wet * (v.x * scale);   // 64B segments
            out[ib] = dry * x[ib] + wet * (v.y * scale);
        }
    }
}

// Correctness fallback if workspace is too small: direct time-domain conv.
__global__ __launch_bounds__(256) void k_direct(const float* __restrict__ x,
                                                const float* __restrict__ ir,
                                                const float* __restrict__ wet_param,
                                                float* __restrict__ out) {
    __shared__ float irs[1024];
    const int b = blockIdx.y;
    const int n = blockIdx.x * 256 + threadIdx.x;
    float acc = 0.0f;
    for (int k0 = 0; k0 < IRL; k0 += 1024) {
        __syncthreads();
        for (int j = threadIdx.x; j < 1024; j += 256) {
            const int k = k0 + j;
            irs[j] = (k < IRL) ? ir[k] : 0.0f;
        }
        __syncthreads();
        if (n < TT) {
            const int kend = min(1024, n - k0 + 1);
            for (int k = 0; k < kend; ++k)
                acc += irs[k] * x[(size_t)b * TT + (n - k0 - k)];
        }
    }
    if (n < TT) {
        const float wet = 1.0f / (1.0f + expf(-wet_param[0]));
        out[(size_t)b * TT + n] = (1.0f - wet) * x[(size_t)b * TT + n] + wet * acc;
    }
}

extern "C" void kernel_launch(void* const* d_in, const int* in_sizes, int n_in,
                              void* d_out, int out_size, void* d_ws, size_t ws_size,
                              hipStream_t stream) {
    (void)in_sizes; (void)n_in; (void)out_size;
    const float* x   = (const float*)d_in[0];
    const float* ir  = (const float*)d_in[1];
    const float* wet = (const float*)d_in[2];
    float* out = (float*)d_out;

    // ws: tw1024(512) + tw512(256) + Ht(NFFT) + bufA(16*NFFT) + bufB(16*NFFT)
    const size_t need = (size_t)(768 + (1 + 2 * NSIG) * (size_t)NFFT) * sizeof(float2);
    if (ws_size < need) {
        dim3 g((TT + 255) / 256, 32);
        k_direct<<<g, 256, 0, stream>>>(x, ir, wet, out);
        return;
    }

    float2* tw1024 = (float2*)d_ws;
    float2* tw512  = tw1024 + 512;
    float2* Ht     = tw1024 + 768;
    float2* bufA   = Ht + NFFT;
    float2* bufB   = bufA + (size_t)NSIG * NFFT;
    float2* irA    = bufB;   // reuse bufB start before it is written

    k_table<<<dim3(2), 256, 0, stream>>>(tw1024);
    k_stage1<<<dim3(N2 / C1, NSIG + 1), 256, 0, stream>>>(x, ir, tw512, bufA, irA);
    k_stage2<<<dim3(N1 / R2), 256, 0, stream>>>(irA, Ht, Ht, tw1024, 0);
    k_stage2<<<dim3(NSIG * N1 / R2), 256, 0, stream>>>(bufA, bufB, Ht, tw1024, 1);
    k_stage3<<<dim3(N2 / C1, NSIG), 256, 0, stream>>>(bufB, x, wet, tw512, out);
}

// Round 3
// 278.145 us; speedup vs baseline: 2.1773x; 1.2730x over previous
//
#include <hip/hip_runtime.h>
#include <math.h>

constexpr int NFFT = 524288;   // 2^19 >= T + L - 1 = 485099
constexpr int N1   = 512;      // column FFT length (strided dim)
constexpr int N2   = 1024;     // row FFT length (contiguous dim)
constexpr int LOG2N2 = 10;
constexpr int TT   = 441000;
constexpr int IRL  = 44100;
constexpr int NSIG = 16;       // 32 real batches packed as 16 complex signals
constexpr int C1   = 16;       // columns per block in stage1/3 (128B segments)
constexpr int R2   = 4;        // rows per block in stage2

// -2*pi/NFFT
constexpr float ANG0 = -1.1984224905891939e-5f;

__device__ inline float2 cmulf(float2 a, float2 b) {
    return make_float2(a.x * b.x - a.y * b.y, a.x * b.y + a.y * b.x);
}
__device__ inline float2 cadd(float2 a, float2 b) { return make_float2(a.x + b.x, a.y + b.y); }
__device__ inline float2 csub(float2 a, float2 b) { return make_float2(a.x - b.x, a.y - b.y); }

// Radix-4 Stockham butterfly. Derived by composing two verified radix-2
// passes (s, then 2s): outputs go to q+4sp+{0,s,2s,3s}, twiddles
// W^{ps}, W^{2ps}, W^{3ps}; cross term -i fwd / +i inv.
// Caller conjugates w1..w3 for the inverse.
template<bool INV>
__device__ inline void bfly4(const float2* u, float2 w1, float2 w2, float2 w3,
                             float2& o0, float2& o1, float2& o2, float2& o3) {
    float2 t0 = cadd(u[0], u[2]);
    float2 t1 = csub(u[0], u[2]);
    float2 t2 = cadd(u[1], u[3]);
    float2 t3 = csub(u[1], u[3]);
    float2 r3 = INV ? make_float2(-t3.y, t3.x) : make_float2(t3.y, -t3.x);
    o0 = cadd(t0, t2);
    o1 = cmulf(cadd(t1, r3), w1);
    o2 = cmulf(csub(t0, t2), w2);
    o3 = cmulf(csub(t1, r3), w3);
}

// tw1024[j] = W_1024^j (1024 entries), then tw512[j] = W_512^j (512 entries).
__global__ __launch_bounds__(256) void k_table(float2* __restrict__ t) {
    int j = blockIdx.x * 256 + threadIdx.x;
    if (j < 1024) {
        float a = -6.2831853071795864769f * (float)j * (1.0f / 1024.0f);
        t[j] = make_float2(cosf(a), sinf(a));
    } else if (j < 1536) {
        int k = j - 1024;
        float a = -6.2831853071795864769f * (float)k * (1.0f / 512.0f);
        t[j] = make_float2(cosf(a), sinf(a));
    }
}

// In-place FFT of 16 sequences of length 512 in one 64KB LDS buffer.
// Element idx of sequence c lives at c*512 + (idx ^ c) (XOR swizzle; c is
// wave-uniform in every access, so within-wave bank patterns are unchanged).
// 4 radix-4 passes + 1 final radix-2 pass (s=256: p=0, unit twiddle, and
// read-set == write-set per thread -> no barrier inside it).
// Thread t owns butterfly f = t&127 of sequences c = (t>>7) + 2k, k=0..7:
// twiddles are loaded once per pass and reused 8x.
template<bool INV>
__device__ void fft512x16_r4(float2* buf, const float2* __restrict__ tw512) {
    const int t  = threadIdx.x;
    const int f  = t & 127;
    const int cb = t >> 7;
    int s = 1, logs = 0;
#pragma unroll
    for (int pass = 0; pass < 4; ++pass) {
        const int p = f >> logs;
        const int q = f & (s - 1);
        const int wb = q + 4 * s * p;
        const int e = p * s;
        float2 w1 = tw512[e], w2 = tw512[2 * e], w3 = tw512[3 * e];
        if (INV) { w1.y = -w1.y; w2.y = -w2.y; w3.y = -w3.y; }
        float2 u[8][4];
#pragma unroll
        for (int k = 0; k < 8; ++k) {
            const int c = cb + 2 * k;
            float2* sb = buf + c * N1;
#pragma unroll
            for (int j = 0; j < 4; ++j) u[k][j] = sb[(f + 128 * j) ^ c];
        }
        __syncthreads();
#pragma unroll
        for (int k = 0; k < 8; ++k) {
            const int c = cb + 2 * k;
            float2* sb = buf + c * N1;
            float2 o0, o1, o2, o3;
            bfly4<INV>(u[k], w1, w2, w3, o0, o1, o2, o3);
            sb[wb ^ c]           = o0;
            sb[(wb + s) ^ c]     = o1;
            sb[(wb + 2 * s) ^ c] = o2;
            sb[(wb + 3 * s) ^ c] = o3;
        }
        __syncthreads();
        s <<= 2; logs += 2;
    }
    // final radix-2, s=256: thread t owns slots {t^c, (t+256)^c} for every c.
#pragma unroll
    for (int c = 0; c < 16; ++c) {
        float2* sb = buf + c * N1;
        float2 a = sb[t ^ c];
        float2 b = sb[(t + 256) ^ c];
        sb[t ^ c]         = cadd(a, b);
        sb[(t + 256) ^ c] = csub(a, b);
    }
    __syncthreads();
}

// In-place FFT of 4 rows of length 1024 in one 32KB LDS buffer (radix-4^5).
// Thread t owns butterfly f = t of every row: twiddles loaded once per pass.
template<bool INV>
__device__ void fft1024x4_r4(float2* buf, const float2* __restrict__ tw1024) {
    const int f = threadIdx.x;   // 0..255 = L/4
    int s = 1, logs = 0;
#pragma unroll
    for (int pass = 0; pass < 5; ++pass) {
        const int p = f >> logs;
        const int q = f & (s - 1);
        const int wb = q + 4 * s * p;
        const int e = p * s;
        float2 w1 = tw1024[e], w2 = tw1024[2 * e], w3 = tw1024[3 * e];
        if (INV) { w1.y = -w1.y; w2.y = -w2.y; w3.y = -w3.y; }
        float2 u[4][4];
#pragma unroll
        for (int r = 0; r < 4; ++r) {
            float2* sb = buf + r * N2;
#pragma unroll
            for (int j = 0; j < 4; ++j) u[r][j] = sb[f + 256 * j];
        }
        __syncthreads();
#pragma unroll
        for (int r = 0; r < 4; ++r) {
            float2* sb = buf + r * N2;
            float2 o0, o1, o2, o3;
            bfly4<INV>(u[r], w1, w2, w3, o0, o1, o2, o3);
            sb[wb]         = o0;
            sb[wb + s]     = o1;
            sb[wb + 2 * s] = o2;
            sb[wb + 3 * s] = o3;
        }
        __syncthreads();
        s <<= 2; logs += 2;
    }
}

// Stage 1 (forward): column FFTs of length N1=512 over n1 (stride N2) for 16
// consecutive n2 per block + inter-stage twiddle W_N^{n2*k1}. Output [k1][n2].
__global__ __launch_bounds__(256) void k_stage1(const float* __restrict__ x,
                                                const float* __restrict__ ir,
                                                const float2* __restrict__ tw512,
                                                float2* __restrict__ bufA,
                                                float2* __restrict__ irA) {
    __shared__ float2 buf[C1 * N1];   // exactly 64 KB
    const int sig  = blockIdx.y;
    const int col0 = blockIdx.x * C1;

#pragma unroll
    for (int it = 0; it < C1 * N1 / 256; ++it) {
        const int p  = threadIdx.x + 256 * it;
        const int c  = p & (C1 - 1);
        const int n1 = p >> 4;
        const int n  = n1 * N2 + col0 + c;      // 64B-contiguous per (n1, batch)
        float2 v = make_float2(0.0f, 0.0f);
        if (sig < NSIG) {
            if (n < TT) {
                v.x = x[(size_t)(2 * sig) * TT + n];
                v.y = x[(size_t)(2 * sig + 1) * TT + n];
            }
        } else {
            if (n < IRL) v.x = ir[n];
        }
        buf[c * N1 + (n1 ^ c)] = v;
    }
    __syncthreads();

    fft512x16_r4<false>(buf, tw512);

    float2* dst = (sig < NSIG) ? (bufA + (size_t)sig * NFFT) : irA;
#pragma unroll
    for (int it = 0; it < C1 * N1 / 256; ++it) {
        const int p  = threadIdx.x + 256 * it;
        const int c  = p & (C1 - 1);
        const int k1 = p >> 4;
        const int n2 = col0 + c;
        float2 v = buf[c * N1 + (k1 ^ c)];
        float ang = ANG0 * (float)(n2 * k1);    // exact: n2*k1 < 2^24
        float sn, cs;
        __sincosf(ang, &sn, &cs);
        dst[(size_t)k1 * N2 + n2] = cmulf(v, make_float2(cs, sn));  // 128B segments
    }
}

// Stage 2: row FFTs of length N2=1024 (contiguous), in-place 32KB.
// mode 0 (IR): forward FFT only -> Ht[k1][k2] (transposed spectrum).
// mode 1 (x) : forward FFT, * Ht, inverse FFT, conj twiddle W_N^{-n2*k1}.
__global__ __launch_bounds__(256) void k_stage2(const float2* __restrict__ src,
                                                float2* __restrict__ dst,
                                                const float2* __restrict__ Ht,
                                                const float2* __restrict__ tw1024,
                                                int mode) {
    __shared__ float2 buf[R2 * N2];   // 32 KB
    const int r0 = blockIdx.x * R2;   // flat row = sig*N1 + k1 (mode1) or k1 (mode0)

    for (int p = threadIdx.x; p < R2 * N2; p += 256) {
        const int rr = p >> LOG2N2, k2 = p & (N2 - 1);
        buf[rr * N2 + k2] = src[(size_t)(r0 + rr) * N2 + k2];
    }
    __syncthreads();

    fft1024x4_r4<false>(buf, tw1024);

    if (mode == 0) {
        for (int p = threadIdx.x; p < R2 * N2; p += 256) {
            const int rr = p >> LOG2N2, k2 = p & (N2 - 1);
            dst[(size_t)(r0 + rr) * N2 + k2] = buf[rr * N2 + k2];
        }
        return;
    }

    for (int p = threadIdx.x; p < R2 * N2; p += 256) {
        const int rr = p >> LOG2N2, k2 = p & (N2 - 1);
        const int k1 = (r0 + rr) & (N1 - 1);
        const int li = rr * N2 + k2;
        buf[li] = cmulf(buf[li], Ht[(size_t)k1 * N2 + k2]);
    }
    __syncthreads();

    fft1024x4_r4<true>(buf, tw1024);

    for (int p = threadIdx.x; p < R2 * N2; p += 256) {
        const int rr = p >> LOG2N2, n2 = p & (N2 - 1);
        const int k1 = (r0 + rr) & (N1 - 1);
        float2 v = buf[rr * N2 + n2];
        float ang = -ANG0 * (float)(n2 * k1);   // conjugate twiddle
        float sn, cs;
        __sincosf(ang, &sn, &cs);
        dst[(size_t)(r0 + rr) * N2 + n2] = cmulf(v, make_float2(cs, sn));
    }
}

// Stage 3 (inverse): column IFFTs over k1 for 16 consecutive n2 per block,
// scale 1/N, unpack complex -> two real batches, fuse wet/dry mix.
__global__ __launch_bounds__(256) void k_stage3(const float2* __restrict__ bufB,
                                                const float* __restrict__ x,
                                                const float* __restrict__ wet_param,
                                                const float2* __restrict__ tw512,
                                                float* __restrict__ out) {
    __shared__ float2 buf[C1 * N1];   // exactly 64 KB
    const int sig  = blockIdx.y;
    const int col0 = blockIdx.x * C1;

    const float2* src = bufB + (size_t)sig * NFFT;
#pragma unroll
    for (int it = 0; it < C1 * N1 / 256; ++it) {
        const int p  = threadIdx.x + 256 * it;
        const int c  = p & (C1 - 1);
        const int k1 = p >> 4;
        buf[c * N1 + (k1 ^ c)] = src[(size_t)k1 * N2 + col0 + c];   // 128B segments
    }
    __syncthreads();

    fft512x16_r4<true>(buf, tw512);

    const float wet = 1.0f / (1.0f + expf(-wet_param[0]));
    const float dry = 1.0f - wet;
    const float scale = 1.0f / (float)NFFT;

#pragma unroll
    for (int it = 0; it < C1 * N1 / 256; ++it) {
        const int p  = threadIdx.x + 256 * it;
        const int c  = p & (C1 - 1);
        const int n1 = p >> 4;
        const int n  = n1 * N2 + col0 + c;
        if (n < TT) {
            float2 v = buf[c * N1 + (n1 ^ c)];
            const size_t ia = (size_t)(2 * sig) * TT + n;
            const size_t ib = ia + TT;
            out[ia] = dry * x[ia] + wet * (v.x * scale);   // 64B segments
            out[ib] = dry * x[ib] + wet * (v.y * scale);
        }
    }
}

// Correctness fallback if workspace is too small: direct time-domain conv.
__global__ __launch_bounds__(256) void k_direct(const float* __restrict__ x,
                                                const float* __restrict__ ir,
                                                const float* __restrict__ wet_param,
                                                float* __restrict__ out) {
    __shared__ float irs[1024];
    const int b = blockIdx.y;
    const int n = blockIdx.x * 256 + threadIdx.x;
    float acc = 0.0f;
    for (int k0 = 0; k0 < IRL; k0 += 1024) {
        __syncthreads();
        for (int j = threadIdx.x; j < 1024; j += 256) {
            const int k = k0 + j;
            irs[j] = (k < IRL) ? ir[k] : 0.0f;
        }
        __syncthreads();
        if (n < TT) {
            const int kend = min(1024, n - k0 + 1);
            for (int k = 0; k < kend; ++k)
                acc += irs[k] * x[(size_t)b * TT + (n - k0 - k)];
        }
    }
    if (n < TT) {
        const float wet = 1.0f / (1.0f + expf(-wet_param[0]));
        out[(size_t)b * TT + n] = (1.0f - wet) * x[(size_t)b * TT + n] + wet * acc;
    }
}

extern "C" void kernel_launch(void* const* d_in, const int* in_sizes, int n_in,
                              void* d_out, int out_size, void* d_ws, size_t ws_size,
                              hipStream_t stream) {
    (void)in_sizes; (void)n_in; (void)out_size;
    const float* x   = (const float*)d_in[0];
    const float* ir  = (const float*)d_in[1];
    const float* wet = (const float*)d_in[2];
    float* out = (float*)d_out;

    // ws: tw1024(1024) + tw512(512) + Ht(NFFT) + bufA(16*NFFT) + bufB(16*NFFT)
    const size_t need = (size_t)(1536 + (1 + 2 * NSIG) * (size_t)NFFT) * sizeof(float2);
    if (ws_size < need) {
        dim3 g((TT + 255) / 256, 32);
        k_direct<<<g, 256, 0, stream>>>(x, ir, wet, out);
        return;
    }

    float2* tw1024 = (float2*)d_ws;
    float2* tw512  = tw1024 + 1024;
    float2* Ht     = tw1024 + 1536;
    float2* bufA   = Ht + NFFT;
    float2* bufB   = bufA + (size_t)NSIG * NFFT;
    float2* irA    = bufB;   // reuse bufB start before it is written

    k_table<<<dim3(6), 256, 0, stream>>>(tw1024);
    k_stage1<<<dim3(N2 / C1, NSIG + 1), 256, 0, stream>>>(x, ir, tw512, bufA, irA);
    k_stage2<<<dim3(N1 / R2), 256, 0, stream>>>(irA, Ht, Ht, tw1024, 0);
    k_stage2<<<dim3(NSIG * N1 / R2), 256, 0, stream>>>(bufA, bufB, Ht, tw1024, 1);
    k_stage3<<<dim3(N2 / C1, NSIG), 256, 0, stream>>>(bufB, x, wet, tw512, out);
}

// Round 4
// 230.273 us; speedup vs baseline: 2.6300x; 1.2079x over previous
//
#include <hip/hip_runtime.h>
#include <math.h>

constexpr int NFFT = 524288;   // 2^19 >= T + L - 1 = 485099
constexpr int N1   = 512;      // column FFT length (strided dim)
constexpr int N2   = 1024;     // row FFT length (contiguous dim)
constexpr int TT   = 441000;   // multiple of 4
constexpr int IRL  = 44100;    // multiple of 4
constexpr int NSIG = 16;       // 32 real batches packed as 16 complex signals
constexpr int C1   = 16;       // columns per block in stage1/3
constexpr int R2   = 4;        // rows per block in stage2

// -2*pi/NFFT
constexpr float ANG0 = -1.1984224905891939e-5f;

__device__ inline float2 cmulf(float2 a, float2 b) {
    return make_float2(a.x * b.x - a.y * b.y, a.x * b.y + a.y * b.x);
}
__device__ inline float2 cadd(float2 a, float2 b) { return make_float2(a.x + b.x, a.y + b.y); }
__device__ inline float2 csub(float2 a, float2 b) { return make_float2(a.x - b.x, a.y - b.y); }

// Radix-4 Stockham butterfly (validated in round 3). Outputs to q+4sp+{0,s,2s,3s},
// twiddles W^{ps},W^{2ps},W^{3ps}; cross term -i fwd / +i inv (caller conjugates w).
template<bool INV>
__device__ inline void bfly4(const float2* u, float2 w1, float2 w2, float2 w3, float2* o) {
    float2 t0 = cadd(u[0], u[2]);
    float2 t1 = csub(u[0], u[2]);
    float2 t2 = cadd(u[1], u[3]);
    float2 t3 = csub(u[1], u[3]);
    float2 r3 = INV ? make_float2(-t3.y, t3.x) : make_float2(t3.y, -t3.x);
    o[0] = cadd(t0, t2);
    o[1] = cmulf(cadd(t1, r3), w1);
    o[2] = cmulf(csub(t0, t2), w2);
    o[3] = cmulf(csub(t1, r3), w3);
}
// Unit-twiddle variant (the s = L/4 final pass has p=0 -> w=1).
template<bool INV>
__device__ inline void bfly4_nw(const float2* u, float2* o) {
    float2 t0 = cadd(u[0], u[2]);
    float2 t1 = csub(u[0], u[2]);
    float2 t2 = cadd(u[1], u[3]);
    float2 t3 = csub(u[1], u[3]);
    float2 r3 = INV ? make_float2(-t3.y, t3.x) : make_float2(t3.y, -t3.x);
    o[0] = cadd(t0, t2);
    o[1] = cadd(t1, r3);
    o[2] = csub(t0, t2);
    o[3] = csub(t1, r3);
}

// tw1024[j] = W_1024^j (1024 entries), then tw512[j] = W_512^j (512 entries).
__global__ __launch_bounds__(256) void k_table(float2* __restrict__ t) {
    int j = blockIdx.x * 256 + threadIdx.x;
    if (j < 1024) {
        float a = -6.2831853071795864769f * (float)j * (1.0f / 1024.0f);
        t[j] = make_float2(cosf(a), sinf(a));
    } else if (j < 1536) {
        int k = j - 1024;
        float a = -6.2831853071795864769f * (float)k * (1.0f / 512.0f);
        t[j] = make_float2(cosf(a), sinf(a));
    }
}

// First 4 radix-4 passes (s=1,4,16,64) of the 512-FFT over 16 XOR-swizzled
// sequences, 512 threads: thread owns butterfly f = t&127 of seqs cb+4k.
template<bool INV>
__device__ void fft512_4passes(float2* buf, const float2* __restrict__ tw512, int tid) {
    const int f  = tid & 127;
    const int cb = tid >> 7;          // 0..3 (wave-uniform)
    int s = 1, logs = 0;
#pragma unroll
    for (int pass = 0; pass < 4; ++pass) {
        const int p = f >> logs;
        const int q = f & (s - 1);
        const int wb = q + 4 * s * p;
        const int e = p * s;
        float2 w1 = tw512[e], w2 = tw512[2 * e], w3 = tw512[3 * e];
        if (INV) { w1.y = -w1.y; w2.y = -w2.y; w3.y = -w3.y; }
        float2 u[4][4];
#pragma unroll
        for (int k = 0; k < 4; ++k) {
            const int c = cb + 4 * k;
            float2* sb = buf + c * N1;
#pragma unroll
            for (int j = 0; j < 4; ++j) u[k][j] = sb[(f + 128 * j) ^ c];
        }
        __syncthreads();
#pragma unroll
        for (int k = 0; k < 4; ++k) {
            const int c = cb + 4 * k;
            float2* sb = buf + c * N1;
            float2 o[4];
            bfly4<INV>(u[k], w1, w2, w3, o);
            sb[wb ^ c]           = o[0];
            sb[(wb + s) ^ c]     = o[1];
            sb[(wb + 2 * s) ^ c] = o[2];
            sb[(wb + 3 * s) ^ c] = o[3];
        }
        __syncthreads();
        s <<= 2; logs += 2;
    }
}

// Radix-4 passes [FIRST, FIRST+COUNT) of the 1024-FFT over 4 rows, 512 threads:
// thread owns butterfly f = t&255 of rows rb+2k.
template<bool INV, int FIRST, int COUNT>
__device__ void fft1024_mid(float2* buf, const float2* __restrict__ tw1024, int tid) {
    const int f  = tid & 255;
    const int rb = tid >> 8;          // 0..1
    int s = 1 << (2 * FIRST), logs = 2 * FIRST;
#pragma unroll
    for (int pass = 0; pass < COUNT; ++pass) {
        const int p = f >> logs;
        const int q = f & (s - 1);
        const int wb = q + 4 * s * p;
        const int e = p * s;
        float2 w1 = tw1024[e], w2 = tw1024[2 * e], w3 = tw1024[3 * e];
        if (INV) { w1.y = -w1.y; w2.y = -w2.y; w3.y = -w3.y; }
        float2 u[2][4];
#pragma unroll
        for (int k = 0; k < 2; ++k) {
            float2* sb = buf + (rb + 2 * k) * N2;
#pragma unroll
            for (int j = 0; j < 4; ++j) u[k][j] = sb[f + 256 * j];
        }
        __syncthreads();
#pragma unroll
        for (int k = 0; k < 2; ++k) {
            float2* sb = buf + (rb + 2 * k) * N2;
            float2 o[4];
            bfly4<INV>(u[k], w1, w2, w3, o);
            sb[wb]         = o[0];
            sb[wb + s]     = o[1];
            sb[wb + 2 * s] = o[2];
            sb[wb + 3 * s] = o[3];
        }
        __syncthreads();
        s <<= 2; logs += 2;
    }
}

// Stage 1 (forward): 512-pt column FFTs (stride N2) for 16 consecutive n2 per
// block; float4 loads; final radix-2 fused with inter-stage twiddle + store.
__global__ __launch_bounds__(512) void k_stage1(const float* __restrict__ x,
                                                const float* __restrict__ ir,
                                                const float2* __restrict__ tw512,
                                                float2* __restrict__ bufA,
                                                float2* __restrict__ irA) {
    __shared__ float2 buf[C1 * N1];   // 64 KB
    const int sig  = blockIdx.y;
    const int col0 = blockIdx.x * C1;
    const int tid  = threadIdx.x;

    if (sig < NSIG) {
        const float* xa = x + (size_t)(2 * sig) * TT;
        const float* xb = xa + TT;
#pragma unroll
        for (int it = 0; it < 4; ++it) {
            const int qi = tid + 512 * it;     // 2048 quads
            const int n1 = qi >> 2;
            const int c4 = (qi & 3) * 4;
            const int n  = n1 * N2 + col0 + c4;     // n % 4 == 0
            float4 a4 = make_float4(0.f, 0.f, 0.f, 0.f);
            float4 b4 = a4;
            if (n < TT) {
                a4 = *(const float4*)(xa + n);
                b4 = *(const float4*)(xb + n);
            }
            buf[(c4 + 0) * N1 + (n1 ^ (c4 + 0))] = make_float2(a4.x, b4.x);
            buf[(c4 + 1) * N1 + (n1 ^ (c4 + 1))] = make_float2(a4.y, b4.y);
            buf[(c4 + 2) * N1 + (n1 ^ (c4 + 2))] = make_float2(a4.z, b4.z);
            buf[(c4 + 3) * N1 + (n1 ^ (c4 + 3))] = make_float2(a4.w, b4.w);
        }
    } else {
#pragma unroll
        for (int it = 0; it < 4; ++it) {
            const int qi = tid + 512 * it;
            const int n1 = qi >> 2;
            const int c4 = (qi & 3) * 4;
            const int n  = n1 * N2 + col0 + c4;
            float4 a4 = make_float4(0.f, 0.f, 0.f, 0.f);
            if (n < IRL) a4 = *(const float4*)(ir + n);
            buf[(c4 + 0) * N1 + (n1 ^ (c4 + 0))] = make_float2(a4.x, 0.f);
            buf[(c4 + 1) * N1 + (n1 ^ (c4 + 1))] = make_float2(a4.y, 0.f);
            buf[(c4 + 2) * N1 + (n1 ^ (c4 + 2))] = make_float2(a4.z, 0.f);
            buf[(c4 + 3) * N1 + (n1 ^ (c4 + 3))] = make_float2(a4.w, 0.f);
        }
    }
    __syncthreads();

    fft512_4passes<false>(buf, tw512, tid);

    // fused: final radix-2 (slots f / f+256, unit twiddle) + W_N^{n2*k1} + store
    float2* dst = (sig < NSIG) ? (bufA + (size_t)sig * NFFT) : irA;
    const int c  = tid & 15;
    const int fr = tid >> 4;          // 0..31
    const int n2 = col0 + c;
#pragma unroll
    for (int it = 0; it < 8; ++it) {
        const int fo = fr + 32 * it;  // 0..255
        float2 a = buf[c * N1 + (fo ^ c)];
        float2 b = buf[c * N1 + ((fo + 256) ^ c)];
        float2 X0 = cadd(a, b);
        float2 X1 = csub(a, b);
        float sn, cs;
        __sincosf(ANG0 * (float)(n2 * fo), &sn, &cs);
        dst[(size_t)fo * N2 + n2] = cmulf(X0, make_float2(cs, sn));
        __sincosf(ANG0 * (float)(n2 * (fo + 256)), &sn, &cs);
        dst[(size_t)(fo + 256) * N2 + n2] = cmulf(X1, make_float2(cs, sn));
    }
}

// Stage 2, mode 0 (IR): forward 1024-FFT only -> Ht (transposed spectrum).
__global__ __launch_bounds__(512) void k_stage2_ir(const float2* __restrict__ src,
                                                   float2* __restrict__ dst,
                                                   const float2* __restrict__ tw1024) {
    __shared__ float2 buf[R2 * N2];   // 32 KB
    const int r0  = blockIdx.x * R2;
    const int tid = threadIdx.x;

#pragma unroll
    for (int it = 0; it < 4; ++it) {
        const int qi = tid + 512 * it;   // 2048 float4 = 4096 float2
        ((float4*)buf)[qi] = ((const float4*)src)[(size_t)r0 * (N2 / 2) + qi];
    }
    __syncthreads();

    fft1024_mid<false, 0, 4>(buf, tw1024, tid);

    // final pass (s=256, unit twiddle) in registers + store (natural order)
    const int f  = tid & 255;
    const int rb = tid >> 8;
#pragma unroll
    for (int k = 0; k < 2; ++k) {
        const int r = rb + 2 * k;
        float2 u[4], o[4];
#pragma unroll
        for (int j = 0; j < 4; ++j) u[j] = buf[r * N2 + f + 256 * j];
        bfly4_nw<false>(u, o);
#pragma unroll
        for (int j = 0; j < 4; ++j)
            dst[(size_t)(r0 + r) * N2 + f + 256 * j] = o[j];
    }
}

// Stage 2, mode 1: fwd 1024-FFT, * Ht, inv 1024-FFT, conj twiddle, store.
// fwd-pass5 + Ht-mult + inv-pass1 fused in registers (s=256 pass is
// per-thread in-place: reads/writes slots f+256j of its own rows).
__global__ __launch_bounds__(512) void k_stage2(const float2* __restrict__ src,
                                                float2* __restrict__ dst,
                                                const float2* __restrict__ Ht,
                                                const float2* __restrict__ tw1024) {
    __shared__ float2 buf[R2 * N2];   // 32 KB
    const int r0  = blockIdx.x * R2;  // flat row = sig*N1 + k1
    const int tid = threadIdx.x;

#pragma unroll
    for (int it = 0; it < 4; ++it) {
        const int qi = tid + 512 * it;
        ((float4*)buf)[qi] = ((const float4*)src)[(size_t)r0 * (N2 / 2) + qi];
    }
    __syncthreads();

    fft1024_mid<false, 0, 4>(buf, tw1024, tid);

    {   // fwd p4 (unit tw) -> * Ht -> inv p0 (tw conj W_1024^{f,2f,3f}), in regs
        const int f  = tid & 255;
        const int rb = tid >> 8;
        float2 u[2][4], h[2][4];
#pragma unroll
        for (int k = 0; k < 2; ++k) {
            const int r  = rb + 2 * k;
            const int k1 = (r0 + r) & (N1 - 1);
#pragma unroll
            for (int j = 0; j < 4; ++j) {
                u[k][j] = buf[r * N2 + f + 256 * j];
                h[k][j] = Ht[(size_t)k1 * N2 + f + 256 * j];
            }
        }
        __syncthreads();   // WAR guard: everyone finished reading old slots
        float2 w1 = tw1024[f], w2 = tw1024[2 * f], w3 = tw1024[3 * f];
        w1.y = -w1.y; w2.y = -w2.y; w3.y = -w3.y;
#pragma unroll
        for (int k = 0; k < 2; ++k) {
            float2 o[4], v[4], o2[4];
            bfly4_nw<false>(u[k], o);
#pragma unroll
            for (int j = 0; j < 4; ++j) v[j] = cmulf(o[j], h[k][j]);
            bfly4<true>(v, w1, w2, w3, o2);
            float2* sb = buf + (rb + 2 * k) * N2;
#pragma unroll
            for (int j = 0; j < 4; ++j) sb[4 * f + j] = o2[j];  // wb=4f, s=1
        }
        __syncthreads();
    }

    fft1024_mid<true, 1, 3>(buf, tw1024, tid);   // inv passes s=4,16,64

    // inv final pass (s=256, unit tw) + conj inter-stage twiddle + store
    const int f  = tid & 255;
    const int rb = tid >> 8;
#pragma unroll
    for (int k = 0; k < 2; ++k) {
        const int r  = rb + 2 * k;
        const int k1 = (r0 + r) & (N1 - 1);
        float2 u[4], o[4];
#pragma unroll
        for (int j = 0; j < 4; ++j) u[j] = buf[r * N2 + f + 256 * j];
        bfly4_nw<true>(u, o);
#pragma unroll
        for (int j = 0; j < 4; ++j) {
            const int n2 = f + 256 * j;
            float sn, cs;
            __sincosf(-ANG0 * (float)(n2 * k1), &sn, &cs);
            dst[(size_t)(r0 + r) * N2 + n2] = cmulf(o[j], make_float2(cs, sn));
        }
    }
}

// Stage 3 (inverse): 512-pt column IFFTs; final radix-2 fused with unpack,
// wet/dry mix and float4 stores.
__global__ __launch_bounds__(512) void k_stage3(const float2* __restrict__ bufB,
                                                const float* __restrict__ x,
                                                const float* __restrict__ wet_param,
                                                const float2* __restrict__ tw512,
                                                float* __restrict__ out) {
    __shared__ float2 buf[C1 * N1];   // 64 KB
    const int sig  = blockIdx.y;
    const int col0 = blockIdx.x * C1;
    const int tid  = threadIdx.x;

    const float2* src = bufB + (size_t)sig * NFFT;
    {
        const int cp  = tid & 7;      // column pair (2 float2 = 1 float4)
        const int k1b = tid >> 3;     // 0..63
#pragma unroll
        for (int it = 0; it < 8; ++it) {
            const int k1 = k1b + 64 * it;
            float4 v = *(const float4*)(src + (size_t)k1 * N2 + col0 + 2 * cp);
            const int ca = 2 * cp, cb2 = 2 * cp + 1;
            buf[ca * N1 + (k1 ^ ca)]   = make_float2(v.x, v.y);
            buf[cb2 * N1 + (k1 ^ cb2)] = make_float2(v.z, v.w);
        }
    }
    __syncthreads();

    fft512_4passes<true>(buf, tw512, tid);

    const float wet = 1.0f / (1.0f + expf(-wet_param[0]));
    const float dry = 1.0f - wet;
    const float ws  = wet * (1.0f / (float)NFFT);

    const float* xa = x + (size_t)(2 * sig) * TT;
    const float* xb = xa + TT;
    float* oa = out + (size_t)(2 * sig) * TT;
    float* ob = oa + TT;

    const int c4 = (tid & 3) * 4;
    const int fr = tid >> 2;          // 0..127
#pragma unroll
    for (int it = 0; it < 2; ++it) {
        const int fo = fr + 128 * it; // 0..255
        float2 y0[4], y1[4];
#pragma unroll
        for (int jj = 0; jj < 4; ++jj) {
            const int c = c4 + jj;
            float2 a = buf[c * N1 + (fo ^ c)];
            float2 b = buf[c * N1 + ((fo + 256) ^ c)];
            y0[jj] = cadd(a, b);      // time row fo
            y1[jj] = csub(a, b);      // time row fo+256
        }
#pragma unroll
        for (int h = 0; h < 2; ++h) {
            const int row = fo + 256 * h;
            const int n   = row * N2 + col0 + c4;   // n % 4 == 0
            if (n < TT) {
                const float2* yy = h ? y1 : y0;
                float4 a4 = *(const float4*)(xa + n);
                float4 b4 = *(const float4*)(xb + n);
                float4 ra, rb2;
                ra.x = dry * a4.x + ws * yy[0].x;
                ra.y = dry * a4.y + ws * yy[1].x;
                ra.z = dry * a4.z + ws * yy[2].x;
                ra.w = dry * a4.w + ws * yy[3].x;
                rb2.x = dry * b4.x + ws * yy[0].y;
                rb2.y = dry * b4.y + ws * yy[1].y;
                rb2.z = dry * b4.z + ws * yy[2].y;
                rb2.w = dry * b4.w + ws * yy[3].y;
                *(float4*)(oa + n) = ra;
                *(float4*)(ob + n) = rb2;
            }
        }
    }
}

// Correctness fallback if workspace is too small: direct time-domain conv.
__global__ __launch_bounds__(256) void k_direct(const float* __restrict__ x,
                                                const float* __restrict__ ir,
                                                const float* __restrict__ wet_param,
                                                float* __restrict__ out) {
    __shared__ float irs[1024];
    const int b = blockIdx.y;
    const int n = blockIdx.x * 256 + threadIdx.x;
    float acc = 0.0f;
    for (int k0 = 0; k0 < IRL; k0 += 1024) {
        __syncthreads();
        for (int j = threadIdx.x; j < 1024; j += 256) {
            const int k = k0 + j;
            irs[j] = (k < IRL) ? ir[k] : 0.0f;
        }
        __syncthreads();
        if (n < TT) {
            const int kend = min(1024, n - k0 + 1);
            for (int k = 0; k < kend; ++k)
                acc += irs[k] * x[(size_t)b * TT + (n - k0 - k)];
        }
    }
    if (n < TT) {
        const float wet = 1.0f / (1.0f + expf(-wet_param[0]));
        out[(size_t)b * TT + n] = (1.0f - wet) * x[(size_t)b * TT + n] + wet * acc;
    }
}

extern "C" void kernel_launch(void* const* d_in, const int* in_sizes, int n_in,
                              void* d_out, int out_size, void* d_ws, size_t ws_size,
                              hipStream_t stream) {
    (void)in_sizes; (void)n_in; (void)out_size;
    const float* x   = (const float*)d_in[0];
    const float* ir  = (const float*)d_in[1];
    const float* wet = (const float*)d_in[2];
    float* out = (float*)d_out;

    // ws: tw1024(1024) + tw512(512) + Ht(NFFT) + bufA(16*NFFT) + bufB(16*NFFT)
    const size_t need = (size_t)(1536 + (1 + 2 * NSIG) * (size_t)NFFT) * sizeof(float2);
    if (ws_size < need) {
        dim3 g((TT + 255) / 256, 32);
        k_direct<<<g, 256, 0, stream>>>(x, ir, wet, out);
        return;
    }

    float2* tw1024 = (float2*)d_ws;
    float2* tw512  = tw1024 + 1024;
    float2* Ht     = tw1024 + 1536;
    float2* bufA   = Ht + NFFT;
    float2* bufB   = bufA + (size_t)NSIG * NFFT;
    float2* irA    = bufB;   // reuse bufB start before it is written

    k_table<<<dim3(6), 256, 0, stream>>>(tw1024);
    k_stage1<<<dim3(N2 / C1, NSIG + 1), 512, 0, stream>>>(x, ir, tw512, bufA, irA);
    k_stage2_ir<<<dim3(N1 / R2), 512, 0, stream>>>(irA, Ht, tw1024);
    k_stage2<<<dim3(NSIG * N1 / R2), 512, 0, stream>>>(bufA, bufB, Ht, tw1024);
    k_stage3<<<dim3(N2 / C1, NSIG), 512, 0, stream>>>(bufB, x, wet, tw512, out);
}

// Round 5
// 213.690 us; speedup vs baseline: 2.8340x; 1.0776x over previous
//
#include <hip/hip_runtime.h>
#include <math.h>

constexpr int NFFT = 524288;   // 2^19 >= T + L - 1 = 485099
constexpr int N1   = 512;      // column FFT length (strided dim)
constexpr int N2   = 1024;     // row FFT length (contiguous dim)
constexpr int TT   = 441000;   // multiple of 4
constexpr int IRL  = 44100;    // multiple of 4
constexpr int NSIG = 16;       // 32 real batches packed as 16 complex signals
constexpr int C1   = 16;       // columns per block in stage1/3
constexpr int R2   = 4;        // rows per block in stage2

// -2*pi/NFFT
constexpr float ANG0   = -1.1984224905891939e-5f;
constexpr float NTWOPI = -6.2831853071795864769f;

__device__ inline float2 cmulf(float2 a, float2 b) {
    return make_float2(a.x * b.x - a.y * b.y, a.x * b.y + a.y * b.x);
}
__device__ inline float2 cadd(float2 a, float2 b) { return make_float2(a.x + b.x, a.y + b.y); }
__device__ inline float2 csub(float2 a, float2 b) { return make_float2(a.x - b.x, a.y - b.y); }

// Radix-4 Stockham butterfly (validated rounds 3-4). Outputs to q+4sp+{0,s,2s,3s},
// twiddles W^{ps},W^{2ps},W^{3ps}; cross term -i fwd / +i inv (caller conjugates w).
template<bool INV>
__device__ inline void bfly4(const float2* u, float2 w1, float2 w2, float2 w3, float2* o) {
    float2 t0 = cadd(u[0], u[2]);
    float2 t1 = csub(u[0], u[2]);
    float2 t2 = cadd(u[1], u[3]);
    float2 t3 = csub(u[1], u[3]);
    float2 r3 = INV ? make_float2(-t3.y, t3.x) : make_float2(t3.y, -t3.x);
    o[0] = cadd(t0, t2);
    o[1] = cmulf(cadd(t1, r3), w1);
    o[2] = cmulf(csub(t0, t2), w2);
    o[3] = cmulf(csub(t1, r3), w3);
}
// Unit-twiddle variant (s = L/4 final pass: p=0 -> w=1).
template<bool INV>
__device__ inline void bfly4_nw(const float2* u, float2* o) {
    float2 t0 = cadd(u[0], u[2]);
    float2 t1 = csub(u[0], u[2]);
    float2 t2 = cadd(u[1], u[3]);
    float2 t3 = csub(u[1], u[3]);
    float2 r3 = INV ? make_float2(-t3.y, t3.x) : make_float2(t3.y, -t3.x);
    o[0] = cadd(t0, t2);
    o[1] = cadd(t1, r3);
    o[2] = csub(t0, t2);
    o[3] = csub(t1, r3);
}

// First 4 radix-4 passes (s=1,4,16,64) of the 512-FFT over 16 XOR-swizzled
// sequences; 1024 threads: thread owns butterfly f = t&127 of seqs cb, cb+8.
template<bool INV>
__device__ void fft512_4p(float2* buf, const float2* __restrict__ tw, int tid) {
    const int f  = tid & 127;
    const int cb = tid >> 7;          // 0..7 (wave-uniform)
    int s = 1, logs = 0;
#pragma unroll
    for (int pass = 0; pass < 4; ++pass) {
        const int p = f >> logs;
        const int q = f & (s - 1);
        const int wb = q + 4 * s * p;
        const int e = p * s;
        float2 w1 = tw[e], w2 = tw[2 * e], w3 = tw[3 * e];
        if (INV) { w1.y = -w1.y; w2.y = -w2.y; w3.y = -w3.y; }
        float2 u[2][4];
#pragma unroll
        for (int k = 0; k < 2; ++k) {
            const int c = cb + 8 * k;
            float2* sb = buf + c * N1;
#pragma unroll
            for (int j = 0; j < 4; ++j) u[k][j] = sb[(f + 128 * j) ^ c];
        }
        __syncthreads();
#pragma unroll
        for (int k = 0; k < 2; ++k) {
            const int c = cb + 8 * k;
            float2* sb = buf + c * N1;
            float2 o[4];
            bfly4<INV>(u[k], w1, w2, w3, o);
            sb[wb ^ c]           = o[0];
            sb[(wb + s) ^ c]     = o[1];
            sb[(wb + 2 * s) ^ c] = o[2];
            sb[(wb + 3 * s) ^ c] = o[3];
        }
        __syncthreads();
        s <<= 2; logs += 2;
    }
}

// Radix-4 passes [FIRST, FIRST+COUNT) of the 1024-FFT over 4 rows; 1024
// threads: thread owns butterfly f = t&255 of row r = t>>8.
template<bool INV, int FIRST, int COUNT>
__device__ void fft1024_mid(float2* buf, const float2* __restrict__ tw, int tid) {
    const int f = tid & 255;
    const int r = tid >> 8;           // 0..3
    float2* sb = buf + r * N2;
    int s = 1 << (2 * FIRST), logs = 2 * FIRST;
#pragma unroll
    for (int pass = 0; pass < COUNT; ++pass) {
        const int p = f >> logs;
        const int q = f & (s - 1);
        const int wb = q + 4 * s * p;
        const int e = p * s;
        float2 w1 = tw[e], w2 = tw[2 * e], w3 = tw[3 * e];
        if (INV) { w1.y = -w1.y; w2.y = -w2.y; w3.y = -w3.y; }
        float2 u[4];
#pragma unroll
        for (int j = 0; j < 4; ++j) u[j] = sb[f + 256 * j];
        __syncthreads();
        float2 o[4];
        bfly4<INV>(u, w1, w2, w3, o);
        sb[wb]         = o[0];
        sb[wb + s]     = o[1];
        sb[wb + 2 * s] = o[2];
        sb[wb + 3 * s] = o[3];
        __syncthreads();
        s <<= 2; logs += 2;
    }
}

// Stage 1 (forward): 512-pt column FFTs (stride N2) for 16 consecutive n2 per
// block; float4 loads; final radix-2 fused with inter-stage twiddle + store.
__global__ __launch_bounds__(1024) void k_stage1(const float* __restrict__ x,
                                                 const float* __restrict__ ir,
                                                 float2* __restrict__ bufA,
                                                 float2* __restrict__ irA) {
    __shared__ float2 buf[C1 * N1];   // 64 KB
    __shared__ float2 tw[N1];         // 4 KB, W_512^j
    const int sig  = blockIdx.y;
    const int col0 = blockIdx.x * C1;
    const int tid  = threadIdx.x;

    if (tid < N1) {
        float sn, cs;
        __sincosf(NTWOPI * (float)tid * (1.0f / (float)N1), &sn, &cs);
        tw[tid] = make_float2(cs, sn);
    }

    if (sig < NSIG) {
        const float* xa = x + (size_t)(2 * sig) * TT;
        const float* xb = xa + TT;
#pragma unroll
        for (int it = 0; it < 2; ++it) {
            const int qi = tid + 1024 * it;     // 2048 quads
            const int n1 = qi >> 2;
            const int c4 = (qi & 3) * 4;
            const int n  = n1 * N2 + col0 + c4; // n % 4 == 0
            float4 a4 = make_float4(0.f, 0.f, 0.f, 0.f);
            float4 b4 = a4;
            if (n < TT) {
                a4 = *(const float4*)(xa + n);
                b4 = *(const float4*)(xb + n);
            }
            buf[(c4 + 0) * N1 + (n1 ^ (c4 + 0))] = make_float2(a4.x, b4.x);
            buf[(c4 + 1) * N1 + (n1 ^ (c4 + 1))] = make_float2(a4.y, b4.y);
            buf[(c4 + 2) * N1 + (n1 ^ (c4 + 2))] = make_float2(a4.z, b4.z);
            buf[(c4 + 3) * N1 + (n1 ^ (c4 + 3))] = make_float2(a4.w, b4.w);
        }
    } else {
#pragma unroll
        for (int it = 0; it < 2; ++it) {
            const int qi = tid + 1024 * it;
            const int n1 = qi >> 2;
            const int c4 = (qi & 3) * 4;
            const int n  = n1 * N2 + col0 + c4;
            float4 a4 = make_float4(0.f, 0.f, 0.f, 0.f);
            if (n < IRL) a4 = *(const float4*)(ir + n);
            buf[(c4 + 0) * N1 + (n1 ^ (c4 + 0))] = make_float2(a4.x, 0.f);
            buf[(c4 + 1) * N1 + (n1 ^ (c4 + 1))] = make_float2(a4.y, 0.f);
            buf[(c4 + 2) * N1 + (n1 ^ (c4 + 2))] = make_float2(a4.z, 0.f);
            buf[(c4 + 3) * N1 + (n1 ^ (c4 + 3))] = make_float2(a4.w, 0.f);
        }
    }
    __syncthreads();

    fft512_4p<false>(buf, tw, tid);

    // fused: final radix-2 (slots f / f+256) + W_N^{n2*k1} twiddle + store.
    // Twiddle recurrence: W^{n2(fr+64it)} = W^{n2*fr} * (W^{64n2})^it,
    // second output uses * W^{256n2}. All integer products < 2^24 (exact).
    float2* dst = (sig < NSIG) ? (bufA + (size_t)sig * NFFT) : irA;
    const int c  = tid & 15;
    const int fr = tid >> 4;          // 0..63
    const int n2 = col0 + c;
    float2 w0, s64, s256;
    {
        float sn, cs;
        __sincosf(ANG0 * (float)(n2 * fr), &sn, &cs);   w0   = make_float2(cs, sn);
        __sincosf(ANG0 * (float)(n2 * 64), &sn, &cs);   s64  = make_float2(cs, sn);
        __sincosf(ANG0 * (float)(n2 * 256), &sn, &cs);  s256 = make_float2(cs, sn);
    }
#pragma unroll
    for (int it = 0; it < 4; ++it) {
        const int fo = fr + 64 * it;  // 0..255
        float2 a = buf[c * N1 + (fo ^ c)];
        float2 b = buf[c * N1 + ((fo + 256) ^ c)];
        float2 X0 = cadd(a, b);
        float2 X1 = csub(a, b);
        dst[(size_t)fo * N2 + n2]         = cmulf(X0, w0);
        dst[(size_t)(fo + 256) * N2 + n2] = cmulf(X1, cmulf(w0, s256));
        w0 = cmulf(w0, s64);
    }
}

// Stage 2, IR path: forward 1024-FFT only -> Ht (transposed spectrum).
__global__ __launch_bounds__(1024) void k_stage2_ir(const float2* __restrict__ src,
                                                    float2* __restrict__ dst) {
    __shared__ float2 buf[R2 * N2];   // 32 KB
    __shared__ float2 tw[N2];         // 8 KB, W_1024^j
    const int r0  = blockIdx.x * R2;
    const int tid = threadIdx.x;

    {
        float sn, cs;
        __sincosf(NTWOPI * (float)tid * (1.0f / (float)N2), &sn, &cs);
        tw[tid] = make_float2(cs, sn);
    }
#pragma unroll
    for (int it = 0; it < 2; ++it) {
        const int qi = tid + 1024 * it;   // 2048 float4
        ((float4*)buf)[qi] = ((const float4*)src)[(size_t)r0 * (N2 / 2) + qi];
    }
    __syncthreads();

    fft1024_mid<false, 0, 4>(buf, tw, tid);

    const int f = tid & 255;
    const int r = tid >> 8;
    float2 u[4], o[4];
#pragma unroll
    for (int j = 0; j < 4; ++j) u[j] = buf[r * N2 + f + 256 * j];
    bfly4_nw<false>(u, o);
#pragma unroll
    for (int j = 0; j < 4; ++j)
        dst[(size_t)(r0 + r) * N2 + f + 256 * j] = o[j];
}

// Stage 2: fwd 1024-FFT, * Ht, inv 1024-FFT, conj inter-stage twiddle, store.
// fwd-pass5 + Ht-mult + inv-pass1 fused in registers.
__global__ __launch_bounds__(1024) void k_stage2(const float2* __restrict__ src,
                                                 float2* __restrict__ dst,
                                                 const float2* __restrict__ Ht) {
    __shared__ float2 buf[R2 * N2];   // 32 KB
    __shared__ float2 tw[N2];         // 8 KB
    const int r0  = blockIdx.x * R2;  // flat row = sig*N1 + k1
    const int tid = threadIdx.x;

    {
        float sn, cs;
        __sincosf(NTWOPI * (float)tid * (1.0f / (float)N2), &sn, &cs);
        tw[tid] = make_float2(cs, sn);
    }
#pragma unroll
    for (int it = 0; it < 2; ++it) {
        const int qi = tid + 1024 * it;
        ((float4*)buf)[qi] = ((const float4*)src)[(size_t)r0 * (N2 / 2) + qi];
    }
    __syncthreads();

    fft1024_mid<false, 0, 4>(buf, tw, tid);

    const int f  = tid & 255;
    const int r  = tid >> 8;
    const int k1 = (r0 + r) & (N1 - 1);
    {   // fwd p4 (unit tw) -> * Ht -> inv p0 (conj W_1024^{f,2f,3f}), in regs
        float2 u[4], h[4];
#pragma unroll
        for (int j = 0; j < 4; ++j) {
            u[j] = buf[r * N2 + f + 256 * j];
            h[j] = Ht[(size_t)k1 * N2 + f + 256 * j];
        }
        __syncthreads();   // WAR guard
        float2 w1 = tw[f], w2 = tw[2 * f], w3 = tw[3 * f];
        w1.y = -w1.y; w2.y = -w2.y; w3.y = -w3.y;
        float2 o[4], v[4], o2[4];
        bfly4_nw<false>(u, o);
#pragma unroll
        for (int j = 0; j < 4; ++j) v[j] = cmulf(o[j], h[j]);
        bfly4<true>(v, w1, w2, w3, o2);
        float2* sb = buf + r * N2;
#pragma unroll
        for (int j = 0; j < 4; ++j) sb[4 * f + j] = o2[j];   // wb=4f, s=1
        __syncthreads();
    }

    fft1024_mid<true, 1, 3>(buf, tw, tid);   // inv passes s=4,16,64

    // inv final pass (s=256, unit tw) + conj twiddle recurrence + store:
    // W^{-k1(f+256j)} = W^{-k1 f} * (W^{-256 k1})^j
    float2 u[4], o[4];
#pragma unroll
    for (int j = 0; j < 4; ++j) u[j] = buf[r * N2 + f + 256 * j];
    bfly4_nw<true>(u, o);
    float2 w, st;
    {
        float sn, cs;
        __sincosf(-ANG0 * (float)(f * k1), &sn, &cs);   w  = make_float2(cs, sn);
        __sincosf(-ANG0 * (float)(256 * k1), &sn, &cs); st = make_float2(cs, sn);
    }
#pragma unroll
    for (int j = 0; j < 4; ++j) {
        dst[(size_t)(r0 + r) * N2 + f + 256 * j] = cmulf(o[j], w);
        w = cmulf(w, st);
    }
}

// Stage 3 (inverse): 512-pt column IFFTs; final radix-2 fused with unpack,
// wet/dry mix and float4 stores.
__global__ __launch_bounds__(1024) void k_stage3(const float2* __restrict__ bufB,
                                                 const float* __restrict__ x,
                                                 const float* __restrict__ wet_param,
                                                 float* __restrict__ out) {
    __shared__ float2 buf[C1 * N1];   // 64 KB
    __shared__ float2 tw[N1];         // 4 KB
    const int sig  = blockIdx.y;
    const int col0 = blockIdx.x * C1;
    const int tid  = threadIdx.x;

    if (tid < N1) {
        float sn, cs;
        __sincosf(NTWOPI * (float)tid * (1.0f / (float)N1), &sn, &cs);
        tw[tid] = make_float2(cs, sn);
    }

    const float2* src = bufB + (size_t)sig * NFFT;
    {
        const int cp  = tid & 7;      // column pair (1 float4)
        const int k1b = tid >> 3;     // 0..127
#pragma unroll
        for (int it = 0; it < 4; ++it) {
            const int k1 = k1b + 128 * it;
            float4 v = *(const float4*)(src + (size_t)k1 * N2 + col0 + 2 * cp);
            const int ca = 2 * cp, cb2 = 2 * cp + 1;
            buf[ca * N1 + (k1 ^ ca)]   = make_float2(v.x, v.y);
            buf[cb2 * N1 + (k1 ^ cb2)] = make_float2(v.z, v.w);
        }
    }
    __syncthreads();

    fft512_4p<true>(buf, tw, tid);

    const float wet = 1.0f / (1.0f + expf(-wet_param[0]));
    const float dry = 1.0f - wet;
    const float ws  = wet * (1.0f / (float)NFFT);

    const float* xa = x + (size_t)(2 * sig) * TT;
    const float* xb = xa + TT;
    float* oa = out + (size_t)(2 * sig) * TT;
    float* ob = oa + TT;

    const int c4 = (tid & 3) * 4;
    const int fo = tid >> 2;          // 0..255
    float2 y0[4], y1[4];
#pragma unroll
    for (int jj = 0; jj < 4; ++jj) {
        const int c = c4 + jj;
        float2 a = buf[c * N1 + (fo ^ c)];
        float2 b = buf[c * N1 + ((fo + 256) ^ c)];
        y0[jj] = cadd(a, b);          // time row fo
        y1[jj] = csub(a, b);          // time row fo+256
    }
#pragma unroll
    for (int h = 0; h < 2; ++h) {
        const int row = fo + 256 * h;
        const int n   = row * N2 + col0 + c4;   // n % 4 == 0
        if (n < TT) {
            const float2* yy = h ? y1 : y0;
            float4 a4 = *(const float4*)(xa + n);
            float4 b4 = *(const float4*)(xb + n);
            float4 ra, rb2;
            ra.x = dry * a4.x + ws * yy[0].x;
            ra.y = dry * a4.y + ws * yy[1].x;
            ra.z = dry * a4.z + ws * yy[2].x;
            ra.w = dry * a4.w + ws * yy[3].x;
            rb2.x = dry * b4.x + ws * yy[0].y;
            rb2.y = dry * b4.y + ws * yy[1].y;
            rb2.z = dry * b4.z + ws * yy[2].y;
            rb2.w = dry * b4.w + ws * yy[3].y;
            *(float4*)(oa + n) = ra;
            *(float4*)(ob + n) = rb2;
        }
    }
}

// Correctness fallback if workspace is too small: direct time-domain conv.
__global__ __launch_bounds__(256) void k_direct(const float* __restrict__ x,
                                                const float* __restrict__ ir,
                                                const float* __restrict__ wet_param,
                                                float* __restrict__ out) {
    __shared__ float irs[1024];
    const int b = blockIdx.y;
    const int n = blockIdx.x * 256 + threadIdx.x;
    float acc = 0.0f;
    for (int k0 = 0; k0 < IRL; k0 += 1024) {
        __syncthreads();
        for (int j = threadIdx.x; j < 1024; j += 256) {
            const int k = k0 + j;
            irs[j] = (k < IRL) ? ir[k] : 0.0f;
        }
        __syncthreads();
        if (n < TT) {
            const int kend = min(1024, n - k0 + 1);
            for (int k = 0; k < kend; ++k)
                acc += irs[k] * x[(size_t)b * TT + (n - k0 - k)];
        }
    }
    if (n < TT) {
        const float wet = 1.0f / (1.0f + expf(-wet_param[0]));
        out[(size_t)b * TT + n] = (1.0f - wet) * x[(size_t)b * TT + n] + wet * acc;
    }
}

extern "C" void kernel_launch(void* const* d_in, const int* in_sizes, int n_in,
                              void* d_out, int out_size, void* d_ws, size_t ws_size,
                              hipStream_t stream) {
    (void)in_sizes; (void)n_in; (void)out_size;
    const float* x   = (const float*)d_in[0];
    const float* ir  = (const float*)d_in[1];
    const float* wet = (const float*)d_in[2];
    float* out = (float*)d_out;

    // ws: Ht(NFFT) + bufA(16*NFFT) + bufB(16*NFFT)
    const size_t need = (size_t)(1 + 2 * NSIG) * (size_t)NFFT * sizeof(float2);
    if (ws_size < need) {
        dim3 g((TT + 255) / 256, 32);
        k_direct<<<g, 256, 0, stream>>>(x, ir, wet, out);
        return;
    }

    float2* Ht   = (float2*)d_ws;
    float2* bufA = Ht + NFFT;
    float2* bufB = bufA + (size_t)NSIG * NFFT;
    float2* irA  = bufB;   // reuse bufB start before it is written

    k_stage1<<<dim3(N2 / C1, NSIG + 1), 1024, 0, stream>>>(x, ir, bufA, irA);
    k_stage2_ir<<<dim3(N1 / R2), 1024, 0, stream>>>(irA, Ht);
    k_stage2<<<dim3(NSIG * N1 / R2), 1024, 0, stream>>>(bufA, bufB, Ht);
    k_stage3<<<dim3(N2 / C1, NSIG), 1024, 0, stream>>>(bufB, x, wet, out);
}